// Round 6
// baseline (594.804 us; speedup 1.0000x reference)
//
#include <hip/hip_runtime.h>
#include <hip/hip_bf16.h>
#include <stdint.h>

#define SLEN 2048
#define HIDN 4096
#define NHEAD 32
#define NKV 8
#define HD 128
#define QKV_N 6144

typedef __hip_bfloat16 bf16;
typedef short short8 __attribute__((ext_vector_type(8)));
typedef _Float16 f16x8 __attribute__((ext_vector_type(8)));
typedef float f32x4 __attribute__((ext_vector_type(4)));

__device__ __forceinline__ void gld16(const void* g, void* l) {
  __builtin_amdgcn_global_load_lds((const __attribute__((address_space(1))) void*)g,
                                   (__attribute__((address_space(3))) void*)l,
                                   16, 0, 0);
}

// Swizzled short8/f16x8 read from a [*][128] 2B-elem LDS tile; 16B slots XORed
// with (row&7) within each row (matches the pre-swizzled gld16 source).
__device__ __forceinline__ short8 ldswz(const bf16* s, int row, int elem) {
  return *(const short8*)(s + row * 128 + (elem ^ ((row & 7) << 3)));
}
__device__ __forceinline__ f16x8 ldswzh(const _Float16* s, int row, int elem) {
  return *(const f16x8*)(s + row * 128 + (elem ^ ((row & 7) << 3)));
}

// Plain bf16 MFMA GEMM: C[M,N](fp32) = A[M,K] * B[N,K]^T, K-major operands.
// 128x128 tile, 4 waves, bijective XCD block remap.
__global__ __launch_bounds__(256) void gemm_kernel(
    const bf16* __restrict__ A, const bf16* __restrict__ B,
    float* __restrict__ C, int K, int lda, int ldb, int ldc)
{
  __shared__ __align__(16) bf16 smem[2 * 4096];
  bf16* sA = smem;
  bf16* sB = smem + 4096;

  const int nwg = gridDim.x * gridDim.y;
  int bid = blockIdx.y * gridDim.x + blockIdx.x;
  {
    const int q = nwg >> 3, rr = nwg & 7, x = bid & 7, idx = bid >> 3;
    bid = (x < rr ? x * (q + 1) : rr * (q + 1) + (x - rr) * q) + idx;
  }
  const int bx = bid % gridDim.x;
  const int by = bid / gridDim.x;
  const int row0 = by * 128;
  const int col0 = bx * 128;

  const int tid = threadIdx.x;
  const int w = tid >> 6;
  const int lane = tid & 63;
  const int wr = w >> 1, wc = w & 1;

  f32x4 acc[4][4] = {};

  const int fr = lane & 15;
  const int fk = (lane >> 4) << 3;

  const int nk = K >> 5;
  for (int kt = 0; kt < nk; ++kt) {
    const int k0 = kt << 5;
#pragma unroll
    for (int i = 0; i < 2; ++i) {
      const int grp = (i << 2) + w;
      const int c = grp * 64 + lane;
      const int r = c >> 2;
      const int kk = k0 + ((c & 3) << 3);
      gld16(A + (long)(row0 + r) * lda + kk, sA + grp * 512);
      gld16(B + (long)(col0 + r) * ldb + kk, sB + grp * 512);
    }
    __syncthreads();
    short8 a[4], b[4];
#pragma unroll
    for (int m = 0; m < 4; ++m) {
      a[m] = *(const short8*)(sA + (wr * 64 + m * 16 + fr) * 32 + fk);
      b[m] = *(const short8*)(sB + (wc * 64 + m * 16 + fr) * 32 + fk);
    }
    __builtin_amdgcn_s_setprio(1);
#pragma unroll
    for (int m = 0; m < 4; ++m)
#pragma unroll
      for (int n = 0; n < 4; ++n)
        acc[m][n] = __builtin_amdgcn_mfma_f32_16x16x32_bf16(a[m], b[n], acc[m][n], 0, 0, 0);
    __builtin_amdgcn_s_setprio(0);
    __syncthreads();
  }

  const int cr = (lane >> 4) << 2;
  const int cc = lane & 15;
#pragma unroll
  for (int m = 0; m < 4; ++m)
#pragma unroll
    for (int n = 0; n < 4; ++n)
#pragma unroll
      for (int r = 0; r < 4; ++r) {
        const long row = row0 + wr * 64 + m * 16 + cr + r;
        const long col = col0 + wc * 64 + n * 16 + cc;
        C[row * (long)ldc + col] = acc[m][n][r];
      }
}

// dst[z][n][k] = bf16(src[z][k][n]), fp32 src. 64x64 tiles via LDS.
__global__ __launch_bounds__(256) void transpose_kernel(
    const float* __restrict__ src, long srcZ, int srcLd,
    bf16* __restrict__ dst, long dstZ, int dstLd)
{
  __shared__ float t[64][65];
  const int z = blockIdx.z;
  src += (long)z * srcZ;
  const long db = (long)z * dstZ;
  const int k0 = blockIdx.x * 64;
  const int n0 = blockIdx.y * 64;
  const int tx = threadIdx.x & 63;
  const int ty = threadIdx.x >> 6;
#pragma unroll
  for (int r = ty; r < 64; r += 4)
    t[r][tx] = src[(long)(k0 + r) * srcLd + n0 + tx];
  __syncthreads();
#pragma unroll
  for (int r = ty; r < 64; r += 4)
    dst[db + (long)(n0 + r) * dstLd + k0 + tx] = __float2bfloat16(t[tx][r]);
}

__global__ __launch_bounds__(256) void cvt_bf16_kernel(
    const float* __restrict__ x, bf16* __restrict__ y, int n)
{
  const int i = (blockIdx.x * 256 + threadIdx.x) * 4;
  if (i >= n) return;
  const f32x4 v = *(const f32x4*)(x + i);
#pragma unroll
  for (int j = 0; j < 4; ++j) y[i + j] = __float2bfloat16(v[j]);
}

// One wave per (s, head): RMSNorm over D=128 (fp32) then RoPE; fp16 out [head][s][d].
__global__ __launch_bounds__(256) void rope_norm_kernel(
    const float* __restrict__ x_, int ld, int nh,
    const float* __restrict__ nw, const float* __restrict__ cosb,
    const float* __restrict__ sinb, const float* __restrict__ epsp,
    _Float16* __restrict__ df)
{
  const int gw = blockIdx.x * 4 + (threadIdx.x >> 6);
  const int lane = threadIdx.x & 63;
  const int srow = gw / nh;
  const int head = gw - srow * nh;
  const float* x = x_ + (long)srow * ld + head * HD;
  const float x0 = x[lane];
  const float x1 = x[lane + 64];
  float ss = x0 * x0 + x1 * x1;
#pragma unroll
  for (int o = 32; o > 0; o >>= 1) ss += __shfl_xor(ss, o);
  const float rr = rsqrtf(ss * (1.0f / 128.0f) + epsp[0]);
  const float nv0 = x0 * rr * nw[lane];
  const float nv1 = x1 * rr * nw[lane + 64];
  const float c0 = cosb[srow * HD + lane];
  const float c1 = cosb[srow * HD + lane + 64];
  const float sn0 = sinb[srow * HD + lane];
  const float sn1 = sinb[srow * HD + lane + 64];
  const float o0 = nv0 * c0 - nv1 * sn0;
  const float o1 = nv1 * c1 + nv0 * sn1;
  const long base = ((long)head * SLEN + srow) * HD;
  df[base + lane] = (_Float16)o0;
  df[base + lane + 64] = (_Float16)o1;
}

// Flash attention v2: block = (128 q-rows, head), 4 waves (wave owns 32 rows).
// Q/K fp16 (single-pass QK^T); P/V bf16. LDS 64 KiB (P aliases K region) -> 2 blocks/CU.
__global__ __launch_bounds__(256, 2) void flash_kernel(
    const _Float16* __restrict__ qf, const _Float16* __restrict__ kf,
    const bf16* __restrict__ vt,   // [kvh][d=128][s=2048]
    bf16* __restrict__ AO)         // [2048][4096]
{
  __shared__ __align__(16) _Float16 sK[128 * 128];  // 32KB; P (bf16) aliases after QK reads
  __shared__ __align__(16) bf16 sV[128 * 128];      // 32KB, [d][s-chunk]

  const int qt = blockIdx.x;
  const int head = blockIdx.y;
  const int kvh = head >> 2;
  const int tid = threadIdx.x;
  const int w = tid >> 6;
  const int lane = tid & 63;
  const int fr = lane & 15;
  const int g = lane >> 4;
  const int fk = g << 3;

  // Q fragments (A-layout: row=fr, k=fk..fk+7), rows w*32 + m*16 + fr
  f16x8 aq[2][4];
  {
    const long qb = ((long)head * SLEN + qt * 128 + w * 32 + fr) * HD + fk;
#pragma unroll
    for (int m = 0; m < 2; ++m)
#pragma unroll
      for (int ks = 0; ks < 4; ++ks)
        aq[m][ks] = *(const f16x8*)(qf + qb + m * 16 * HD + ks * 32);
  }

  f32x4 o[2][8] = {};
  float mrow[2][4], lrow[2][4];
#pragma unroll
  for (int m = 0; m < 2; ++m)
#pragma unroll
    for (int r = 0; r < 4; ++r) { mrow[m][r] = -3.0e38f; lrow[m][r] = 0.0f; }

  bf16* sPw = (bf16*)sK + w * 32 * 128;  // per-wave 32x128 P slice (aliases sK)
  const _Float16* kb = kf + (long)kvh * SLEN * HD;
  const bf16* vb = vt + (long)kvh * HD * SLEN;

  for (int t = 0; t < SLEN / 128; ++t) {
    // stage K [key][d] (fp16) and V [d][s] (bf16); source pre-swizzled (rule 21)
#pragma unroll
    for (int i = 0; i < 8; ++i) {
      const int c = i * 256 + tid;
      const int row = c >> 4;
      const int slot = (c & 15) ^ (row & 7);
      const int dstE = (i * 256 + w * 64) * 8;  // wave-uniform dest, lane-linear
      gld16(kb + (long)(t * 128 + row) * HD + slot * 8, sK + dstE);
      gld16(vb + (long)row * SLEN + t * 128 + slot * 8, sV + dstE);
    }
    __syncthreads();  // stage complete

    // S = Q K^T (fp16 single pass)
    f32x4 s[2][8] = {};
    __builtin_amdgcn_s_setprio(1);
#pragma unroll
    for (int n = 0; n < 8; ++n) {
      f16x8 bh[4];
#pragma unroll
      for (int ks = 0; ks < 4; ++ks)
        bh[ks] = ldswzh(sK, n * 16 + fr, ks * 32 + fk);
#pragma unroll
      for (int m = 0; m < 2; ++m)
#pragma unroll
        for (int ks = 0; ks < 4; ++ks)
          s[m][n] = __builtin_amdgcn_mfma_f32_16x16x32_f16(aq[m][ks], bh[ks], s[m][n], 0, 0, 0);
    }
    __builtin_amdgcn_s_setprio(0);
    __syncthreads();  // all waves done reading sK -> safe to overwrite with P

    // online softmax; lane owns rows m*16+g*4+r, cols n*16+fr
#pragma unroll
    for (int m = 0; m < 2; ++m)
#pragma unroll
      for (int r = 0; r < 4; ++r) {
        float mx = s[m][0][r];
#pragma unroll
        for (int n = 1; n < 8; ++n) mx = fmaxf(mx, s[m][n][r]);
        mx = fmaxf(mx, __shfl_xor(mx, 1));
        mx = fmaxf(mx, __shfl_xor(mx, 2));
        mx = fmaxf(mx, __shfl_xor(mx, 4));
        mx = fmaxf(mx, __shfl_xor(mx, 8));
        const float mnew = fmaxf(mrow[m][r], mx);
        const float corr = __expf(mrow[m][r] - mnew);
        mrow[m][r] = mnew;
        float ps = 0.0f;
#pragma unroll
        for (int n = 0; n < 8; ++n) {
          const float p = __expf(s[m][n][r] - mnew);
          s[m][n][r] = p;
          ps += p;
        }
        ps += __shfl_xor(ps, 1);
        ps += __shfl_xor(ps, 2);
        ps += __shfl_xor(ps, 4);
        ps += __shfl_xor(ps, 8);
        lrow[m][r] = lrow[m][r] * corr + ps;
#pragma unroll
        for (int n = 0; n < 8; ++n) o[m][n][r] *= corr;
      }

    // P -> own-wave LDS slice (bf16, swizzled); C-layout -> A-layout transpose
#pragma unroll
    for (int m = 0; m < 2; ++m)
#pragma unroll
      for (int r = 0; r < 4; ++r) {
        const int qr = m * 16 + g * 4 + r;
#pragma unroll
        for (int n = 0; n < 8; ++n) {
          const int col = n * 16 + fr;
          sPw[qr * 128 + (col ^ ((qr & 7) << 3))] = __float2bfloat16(s[m][n][r]);
        }
      }
    // same-wave LDS RAW (proven pattern from round 5)

    // O += P V
    short8 pa[2][4];
#pragma unroll
    for (int m = 0; m < 2; ++m)
#pragma unroll
      for (int ks = 0; ks < 4; ++ks)
        pa[m][ks] = ldswz(sPw, m * 16 + fr, ks * 32 + fk);
    __builtin_amdgcn_s_setprio(1);
#pragma unroll
    for (int n = 0; n < 8; ++n) {
      short8 bv[4];
#pragma unroll
      for (int ks = 0; ks < 4; ++ks)
        bv[ks] = ldswz(sV, n * 16 + fr, ks * 32 + fk);
#pragma unroll
      for (int m = 0; m < 2; ++m)
#pragma unroll
        for (int ks = 0; ks < 4; ++ks)
          o[m][n] = __builtin_amdgcn_mfma_f32_16x16x32_bf16(pa[m][ks], bv[ks], o[m][n], 0, 0, 0);
    }
    __builtin_amdgcn_s_setprio(0);
    __syncthreads();  // P/V reads done -> next stage may overwrite
  }

#pragma unroll
  for (int m = 0; m < 2; ++m)
#pragma unroll
    for (int r = 0; r < 4; ++r) {
      const float inv = 1.0f / lrow[m][r];
      const long row = qt * 128 + w * 32 + m * 16 + g * 4 + r;
#pragma unroll
      for (int n = 0; n < 8; ++n)
        AO[row * HIDN + head * 128 + n * 16 + fr] = __float2bfloat16(o[m][n][r] * inv);
    }
}

extern "C" void kernel_launch(void* const* d_in, const int* in_sizes, int n_in,
                              void* d_out, int out_size, void* d_ws, size_t ws_size,
                              hipStream_t stream)
{
  const float* hs   = (const float*)d_in[0];
  const float* cosb = (const float*)d_in[1];
  const float* sinb = (const float*)d_in[2];
  const float* wq   = (const float*)d_in[3];
  const float* wk   = (const float*)d_in[4];
  const float* wv   = (const float*)d_in[5];
  const float* wo   = (const float*)d_in[6];
  const float* qw   = (const float*)d_in[7];
  const float* kw   = (const float*)d_in[8];
  const float* eps  = (const float*)d_in[9];

  const size_t MB = 1024 * 1024;
  if (ws_size < 116 * MB) return;  // known-good budget
  uint8_t* ws = (uint8_t*)d_ws;

  // phase-1:
  bf16*  hsb = (bf16*)(ws + 0 * MB);        // [2048][4096]        16 MiB
  bf16*  WT  = (bf16*)(ws + 16 * MB);       // [6144][4096]        48 MiB
  float* QKV = (float*)(ws + 64 * MB);      // [2048][6144] f32    48 MiB
  // phase-2 (WT dead after QKV GEMM):
  _Float16* qf = (_Float16*)(ws + 16 * MB); // [32][2048][128]     16 MiB
  _Float16* kf = (_Float16*)(ws + 32 * MB); // [8][2048][128]       4 MiB
  bf16*  Vt  = (bf16*)(ws + 36 * MB);       // [8][128][2048]       4 MiB
  // phase-3 (QKV dead after rope/V-transpose):
  bf16*  AO  = (bf16*)(ws + 64 * MB);       // [2048][4096]        16 MiB
  bf16*  WoT = (bf16*)(ws + 80 * MB);       // [4096][4096]        32 MiB (peak 112 MiB)

  // 1) hs -> bf16
  cvt_bf16_kernel<<<SLEN * HIDN / 4 / 256, 256, 0, stream>>>(hs, hsb, SLEN * HIDN);

  // 2) weight transposes: WT[n][k] = w*[k][n] for [Q|K|V]
  transpose_kernel<<<dim3(64, 64, 1), 256, 0, stream>>>(wq, 0, HIDN, WT, 0, HIDN);
  transpose_kernel<<<dim3(64, 16, 1), 256, 0, stream>>>(wk, 0, 1024, WT + (size_t)4096 * HIDN, 0, HIDN);
  transpose_kernel<<<dim3(64, 16, 1), 256, 0, stream>>>(wv, 0, 1024, WT + (size_t)5120 * HIDN, 0, HIDN);

  // 3) fused QKV projection GEMM (768 blocks)
  gemm_kernel<<<dim3(48, 16, 1), 256, 0, stream>>>(hsb, WT, QKV, HIDN, HIDN, HIDN, QKV_N);

  // 4) RMSNorm + RoPE -> fp16 per-head layouts
  rope_norm_kernel<<<SLEN * NHEAD / 4, 256, 0, stream>>>(QKV, QKV_N, NHEAD, qw, cosb, sinb, eps, qf);
  rope_norm_kernel<<<SLEN * NKV / 4, 256, 0, stream>>>(QKV + 4096, QKV_N, NKV, kw, cosb, sinb, eps, kf);

  // 5) V^T per kv head: QKV[s][5120+kvh*128+d] -> Vt[kvh][d][s]
  transpose_kernel<<<dim3(32, 2, 8), 256, 0, stream>>>(QKV + 5120, 128, QKV_N, Vt, (long)HD * SLEN, SLEN);

  // 6) wo^T (QKV dead now)
  transpose_kernel<<<dim3(64, 64, 1), 256, 0, stream>>>(wo, 0, HIDN, WoT, 0, HIDN);

  // 7) flash attention (512 blocks, 2/CU)
  flash_kernel<<<dim3(16, 32, 1), 256, 0, stream>>>(qf, kf, Vt, AO);

  // 8) output projection -> fp32 d_out
  gemm_kernel<<<dim3(32, 16, 1), 256, 0, stream>>>(AO, WoT, (float*)d_out, HIDN, HIDN, HIDN, HIDN);
}

// Round 7
// 543.691 us; speedup vs baseline: 1.0940x; 1.0940x over previous
//
#include <hip/hip_runtime.h>
#include <hip/hip_bf16.h>
#include <stdint.h>

#define SLEN 2048
#define HIDN 4096
#define NHEAD 32
#define NKV 8
#define HD 128
#define QKV_N 6144

typedef __hip_bfloat16 bf16;
typedef short short8 __attribute__((ext_vector_type(8)));
typedef _Float16 f16x8 __attribute__((ext_vector_type(8)));
typedef float f32x4 __attribute__((ext_vector_type(4)));

__device__ __forceinline__ void gld16(const void* g, void* l) {
  __builtin_amdgcn_global_load_lds((const __attribute__((address_space(1))) void*)g,
                                   (__attribute__((address_space(3))) void*)l,
                                   16, 0, 0);
}

// Plain bf16 MFMA GEMM: C[M,N](fp32) = A[M,K] * B[N,K]^T, K-major operands.
// 128x128 tile, 4 waves, bijective XCD block remap. (m97 structure)
__global__ __launch_bounds__(256) void gemm_kernel(
    const bf16* __restrict__ A, const bf16* __restrict__ B,
    float* __restrict__ C, int K, int lda, int ldb, int ldc)
{
  __shared__ __align__(16) bf16 smem[2 * 4096];
  bf16* sA = smem;
  bf16* sB = smem + 4096;

  const int nwg = gridDim.x * gridDim.y;
  int bid = blockIdx.y * gridDim.x + blockIdx.x;
  {
    const int q = nwg >> 3, rr = nwg & 7, x = bid & 7, idx = bid >> 3;
    bid = (x < rr ? x * (q + 1) : rr * (q + 1) + (x - rr) * q) + idx;
  }
  const int bx = bid % gridDim.x;
  const int by = bid / gridDim.x;
  const int row0 = by * 128;
  const int col0 = bx * 128;

  const int tid = threadIdx.x;
  const int w = tid >> 6;
  const int lane = tid & 63;
  const int wr = w >> 1, wc = w & 1;

  f32x4 acc[4][4] = {};

  const int fr = lane & 15;
  const int fk = (lane >> 4) << 3;

  const int nk = K >> 5;
  for (int kt = 0; kt < nk; ++kt) {
    const int k0 = kt << 5;
#pragma unroll
    for (int i = 0; i < 2; ++i) {
      const int grp = (i << 2) + w;
      const int c = grp * 64 + lane;
      const int r = c >> 2;
      const int kk = k0 + ((c & 3) << 3);
      gld16(A + (long)(row0 + r) * lda + kk, sA + grp * 512);
      gld16(B + (long)(col0 + r) * ldb + kk, sB + grp * 512);
    }
    __syncthreads();
    short8 a[4], b[4];
#pragma unroll
    for (int m = 0; m < 4; ++m) {
      a[m] = *(const short8*)(sA + (wr * 64 + m * 16 + fr) * 32 + fk);
      b[m] = *(const short8*)(sB + (wc * 64 + m * 16 + fr) * 32 + fk);
    }
    __builtin_amdgcn_s_setprio(1);
#pragma unroll
    for (int m = 0; m < 4; ++m)
#pragma unroll
      for (int n = 0; n < 4; ++n)
        acc[m][n] = __builtin_amdgcn_mfma_f32_16x16x32_bf16(a[m], b[n], acc[m][n], 0, 0, 0);
    __builtin_amdgcn_s_setprio(0);
    __syncthreads();
  }

  const int cr = (lane >> 4) << 2;
  const int cc = lane & 15;
#pragma unroll
  for (int m = 0; m < 4; ++m)
#pragma unroll
    for (int n = 0; n < 4; ++n)
#pragma unroll
      for (int r = 0; r < 4; ++r) {
        const long row = row0 + wr * 64 + m * 16 + cr + r;
        const long col = col0 + wc * 64 + n * 16 + cc;
        C[row * (long)ldc + col] = acc[m][n][r];
      }
}

// dst[z][n][k] = bf16(src[z][k][n]), fp32 src. 64x64 tiles via LDS.
__global__ __launch_bounds__(256) void transpose_kernel(
    const float* __restrict__ src, long srcZ, int srcLd,
    bf16* __restrict__ dst, long dstZ, int dstLd)
{
  __shared__ float t[64][65];
  const int z = blockIdx.z;
  src += (long)z * srcZ;
  const long db = (long)z * dstZ;
  const int k0 = blockIdx.x * 64;
  const int n0 = blockIdx.y * 64;
  const int tx = threadIdx.x & 63;
  const int ty = threadIdx.x >> 6;
#pragma unroll
  for (int r = ty; r < 64; r += 4)
    t[r][tx] = src[(long)(k0 + r) * srcLd + n0 + tx];
  __syncthreads();
#pragma unroll
  for (int r = ty; r < 64; r += 4)
    dst[db + (long)(n0 + r) * dstLd + k0 + tx] = __float2bfloat16(t[tx][r]);
}

__global__ __launch_bounds__(256) void cvt_bf16_kernel(
    const float* __restrict__ x, bf16* __restrict__ y, int n)
{
  const int i = (blockIdx.x * 256 + threadIdx.x) * 4;
  if (i >= n) return;
  const f32x4 v = *(const f32x4*)(x + i);
#pragma unroll
  for (int j = 0; j < 4; ++j) y[i + j] = __float2bfloat16(v[j]);
}

// One wave per (s, head): RMSNorm over D=128 (fp32) then RoPE; fp16 out [head][s][d].
__global__ __launch_bounds__(256) void rope_norm_kernel(
    const float* __restrict__ x_, int ld, int nh,
    const float* __restrict__ nw, const float* __restrict__ cosb,
    const float* __restrict__ sinb, const float* __restrict__ epsp,
    _Float16* __restrict__ df)
{
  const int gw = blockIdx.x * 4 + (threadIdx.x >> 6);
  const int lane = threadIdx.x & 63;
  const int srow = gw / nh;
  const int head = gw - srow * nh;
  const float* x = x_ + (long)srow * ld + head * HD;
  const float x0 = x[lane];
  const float x1 = x[lane + 64];
  float ss = x0 * x0 + x1 * x1;
#pragma unroll
  for (int o = 32; o > 0; o >>= 1) ss += __shfl_xor(ss, o);
  const float rr = rsqrtf(ss * (1.0f / 128.0f) + epsp[0]);
  const float nv0 = x0 * rr * nw[lane];
  const float nv1 = x1 * rr * nw[lane + 64];
  const float c0 = cosb[srow * HD + lane];
  const float c1 = cosb[srow * HD + lane + 64];
  const float sn0 = sinb[srow * HD + lane];
  const float sn1 = sinb[srow * HD + lane + 64];
  const float o0 = nv0 * c0 - nv1 * sn0;
  const float o1 = nv1 * c1 + nv0 * sn1;
  const long base = ((long)head * SLEN + srow) * HD;
  df[base + lane] = (_Float16)o0;
  df[base + lane + 64] = (_Float16)o1;
}

// Flash attention v3: block = (128 q-rows, head), 4 waves. KVBLK=64,
// double-buffered K/V staging with counted vmcnt (T3/T4): stage(t+2) issued
// after compute(t); s_waitcnt vmcnt(8) leaves the new loads in flight.
// LDS 80KB -> 2 blocks/CU. Q/K fp16; P/V bf16.
__global__ __launch_bounds__(256, 2) void flash_kernel(
    const _Float16* __restrict__ qf, const _Float16* __restrict__ kf,
    const bf16* __restrict__ vt,   // [kvh][d=128][s=2048]
    bf16* __restrict__ AO)         // [2048][4096]
{
  __shared__ __align__(16) _Float16 sK[2][64 * 128];  // 2 x 16KB, [key][d]
  __shared__ __align__(16) bf16 sV[2][128 * 64];      // 2 x 16KB, [d][s]
  __shared__ __align__(16) bf16 sP[4][32 * 64];       // 16KB, per-wave [q][s]

  // XCD remap: 512 blocks, chunk 64 = one kv-head per XCD (K/V L2-resident).
  const int lin = blockIdx.y * gridDim.x + blockIdx.x;  // head*16 + qt
  const int swz = (lin & 7) * 64 + (lin >> 3);
  const int head = swz >> 4;
  const int qt = swz & 15;
  const int kvh = head >> 2;

  const int tid = threadIdx.x;
  const int w = tid >> 6;
  const int lane = tid & 63;
  const int fr = lane & 15;
  const int g = lane >> 4;
  const int fk = g << 3;

  // Q fragments (A-layout: row=fr, k=fk..fk+7), rows w*32 + m*16 + fr
  f16x8 aq[2][4];
  {
    const long qb = ((long)head * SLEN + qt * 128 + w * 32 + fr) * HD + fk;
#pragma unroll
    for (int m = 0; m < 2; ++m)
#pragma unroll
      for (int ks = 0; ks < 4; ++ks)
        aq[m][ks] = *(const f16x8*)(qf + qb + m * 16 * HD + ks * 32);
  }

  const _Float16* kb = kf + (long)kvh * SLEN * HD;
  const bf16* vb = vt + (long)kvh * HD * SLEN;

  // stage tile t into buffer buf: K [64][128] (16 slots/row, XOR row&15),
  // V [128][64] (8 slots/row, XOR row&7). LDS dest linear; source pre-swizzled.
  auto stage = [&](int t, int buf) {
#pragma unroll
    for (int i = 0; i < 4; ++i) {
      const int c = i * 256 + tid;
      const int row = c >> 4;
      const int slot = (c & 15) ^ (row & 15);
      gld16(kb + (long)(t * 64 + row) * HD + slot * 8,
            (_Float16*)sK[buf] + (i * 256 + w * 64) * 8);
    }
#pragma unroll
    for (int i = 0; i < 4; ++i) {
      const int c = i * 256 + tid;
      const int row = c >> 3;
      const int slot = (c & 7) ^ (row & 7);
      gld16(vb + (long)row * SLEN + t * 64 + slot * 8,
            (bf16*)sV[buf] + (i * 256 + w * 64) * 8);
    }
  };

  f32x4 o[2][8] = {};
  float mrow[2][4], lrow[2][4];
#pragma unroll
  for (int m = 0; m < 2; ++m)
#pragma unroll
    for (int r = 0; r < 4; ++r) { mrow[m][r] = -3.0e38f; lrow[m][r] = 0.0f; }

  bf16* sPw = sP[w];

  // prologue: fill both buffers, wait tile 0 (Q's 8 loads are oldest, drain too)
  stage(0, 0);
  stage(1, 1);
  asm volatile("s_waitcnt vmcnt(8)" ::: "memory");
  __builtin_amdgcn_sched_barrier(0);
  __builtin_amdgcn_s_barrier();
  __builtin_amdgcn_sched_barrier(0);

#pragma unroll 2
  for (int t = 0; t < SLEN / 64; ++t) {
    const int cur = t & 1;
    const _Float16* K = sK[cur];
    const bf16* V = sV[cur];

    // S[32q][64s] = Q K^T (fp16)
    f32x4 s[2][4] = {};
    __builtin_amdgcn_s_setprio(1);
#pragma unroll
    for (int n = 0; n < 4; ++n) {
      f16x8 bh[4];
#pragma unroll
      for (int ks = 0; ks < 4; ++ks) {
        const int row = n * 16 + fr;
        bh[ks] = *(const f16x8*)(K + row * 128 + ((ks * 32 + fk) ^ ((row & 15) << 3)));
      }
#pragma unroll
      for (int m = 0; m < 2; ++m)
#pragma unroll
        for (int ks = 0; ks < 4; ++ks)
          s[m][n] = __builtin_amdgcn_mfma_f32_16x16x32_f16(aq[m][ks], bh[ks], s[m][n], 0, 0, 0);
    }
    __builtin_amdgcn_s_setprio(0);

    // online softmax; lane owns rows m*16+g*4+r, cols n*16+fr
#pragma unroll
    for (int m = 0; m < 2; ++m)
#pragma unroll
      for (int r = 0; r < 4; ++r) {
        float mx = s[m][0][r];
#pragma unroll
        for (int n = 1; n < 4; ++n) mx = fmaxf(mx, s[m][n][r]);
        mx = fmaxf(mx, __shfl_xor(mx, 1));
        mx = fmaxf(mx, __shfl_xor(mx, 2));
        mx = fmaxf(mx, __shfl_xor(mx, 4));
        mx = fmaxf(mx, __shfl_xor(mx, 8));
        const float mnew = fmaxf(mrow[m][r], mx);
        const float corr = __expf(mrow[m][r] - mnew);
        mrow[m][r] = mnew;
        float ps = 0.0f;
#pragma unroll
        for (int n = 0; n < 4; ++n) {
          const float p = __expf(s[m][n][r] - mnew);
          s[m][n][r] = p;
          ps += p;
        }
        ps += __shfl_xor(ps, 1);
        ps += __shfl_xor(ps, 2);
        ps += __shfl_xor(ps, 4);
        ps += __shfl_xor(ps, 8);
        lrow[m][r] = lrow[m][r] * corr + ps;
#pragma unroll
        for (int n = 0; n < 8; ++n) o[m][n][r] *= corr;
      }

    // P -> own-wave LDS slice [32][64] (bf16, XOR row&7)
#pragma unroll
    for (int m = 0; m < 2; ++m)
#pragma unroll
      for (int r = 0; r < 4; ++r) {
        const int qr = m * 16 + g * 4 + r;
#pragma unroll
        for (int n = 0; n < 4; ++n) {
          const int col = n * 16 + fr;
          sPw[qr * 64 + (col ^ ((qr & 7) << 3))] = __float2bfloat16(s[m][n][r]);
        }
      }

    // O[32q][128d] += P V  (P: A-operand from sPw; V^T: B from sV)
    short8 pa[2][2];
#pragma unroll
    for (int m = 0; m < 2; ++m)
#pragma unroll
      for (int ks = 0; ks < 2; ++ks) {
        const int row = m * 16 + fr;
        pa[m][ks] = *(const short8*)(sPw + row * 64 + ((ks * 32 + fk) ^ ((row & 7) << 3)));
      }
    __builtin_amdgcn_s_setprio(1);
#pragma unroll
    for (int n = 0; n < 8; ++n) {
      short8 bv[2];
#pragma unroll
      for (int ks = 0; ks < 2; ++ks) {
        const int row = n * 16 + fr;
        bv[ks] = *(const short8*)(V + row * 64 + ((ks * 32 + fk) ^ ((row & 7) << 3)));
      }
#pragma unroll
      for (int m = 0; m < 2; ++m)
#pragma unroll
        for (int ks = 0; ks < 2; ++ks)
          o[m][n] = __builtin_amdgcn_mfma_f32_16x16x32_bf16(pa[m][ks], bv[ks], o[m][n], 0, 0, 0);
    }
    __builtin_amdgcn_s_setprio(0);

    // all waves done reading buf cur -> refill it for t+2; counted wait for t+1
    __builtin_amdgcn_s_barrier();
    __builtin_amdgcn_sched_barrier(0);
    if (t + 2 < SLEN / 64) {
      stage(t + 2, cur);
      asm volatile("s_waitcnt vmcnt(8)" ::: "memory");
    } else {
      asm volatile("s_waitcnt vmcnt(0)" ::: "memory");
    }
    __builtin_amdgcn_sched_barrier(0);
    __builtin_amdgcn_s_barrier();
    __builtin_amdgcn_sched_barrier(0);
  }

#pragma unroll
  for (int m = 0; m < 2; ++m)
#pragma unroll
    for (int r = 0; r < 4; ++r) {
      const float inv = 1.0f / lrow[m][r];
      const long row = qt * 128 + w * 32 + m * 16 + g * 4 + r;
#pragma unroll
      for (int n = 0; n < 8; ++n)
        AO[row * HIDN + head * 128 + n * 16 + fr] = __float2bfloat16(o[m][n][r] * inv);
    }
}

extern "C" void kernel_launch(void* const* d_in, const int* in_sizes, int n_in,
                              void* d_out, int out_size, void* d_ws, size_t ws_size,
                              hipStream_t stream)
{
  const float* hs   = (const float*)d_in[0];
  const float* cosb = (const float*)d_in[1];
  const float* sinb = (const float*)d_in[2];
  const float* wq   = (const float*)d_in[3];
  const float* wk   = (const float*)d_in[4];
  const float* wv   = (const float*)d_in[5];
  const float* wo   = (const float*)d_in[6];
  const float* qw   = (const float*)d_in[7];
  const float* kw   = (const float*)d_in[8];
  const float* eps  = (const float*)d_in[9];

  const size_t MB = 1024 * 1024;
  if (ws_size < 116 * MB) return;  // known-good budget
  uint8_t* ws = (uint8_t*)d_ws;

  // phase-1:
  bf16*  hsb = (bf16*)(ws + 0 * MB);        // [2048][4096]        16 MiB
  bf16*  WT  = (bf16*)(ws + 16 * MB);       // [6144][4096]        48 MiB
  float* QKV = (float*)(ws + 64 * MB);      // [2048][6144] f32    48 MiB
  // phase-2 (WT dead after QKV GEMM):
  _Float16* qf = (_Float16*)(ws + 16 * MB); // [32][2048][128]     16 MiB
  _Float16* kf = (_Float16*)(ws + 32 * MB); // [8][2048][128]       4 MiB
  bf16*  Vt  = (bf16*)(ws + 36 * MB);       // [8][128][2048]       4 MiB
  // phase-3 (QKV dead after rope/V-transpose):
  bf16*  AO  = (bf16*)(ws + 64 * MB);       // [2048][4096]        16 MiB
  bf16*  WoT = (bf16*)(ws + 80 * MB);       // [4096][4096]        32 MiB (peak 112 MiB)

  // 1) hs -> bf16
  cvt_bf16_kernel<<<SLEN * HIDN / 4 / 256, 256, 0, stream>>>(hs, hsb, SLEN * HIDN);

  // 2) weight transposes: WT[n][k] = w*[k][n] for [Q|K|V]
  transpose_kernel<<<dim3(64, 64, 1), 256, 0, stream>>>(wq, 0, HIDN, WT, 0, HIDN);
  transpose_kernel<<<dim3(64, 16, 1), 256, 0, stream>>>(wk, 0, 1024, WT + (size_t)4096 * HIDN, 0, HIDN);
  transpose_kernel<<<dim3(64, 16, 1), 256, 0, stream>>>(wv, 0, 1024, WT + (size_t)5120 * HIDN, 0, HIDN);

  // 3) fused QKV projection GEMM (768 blocks)
  gemm_kernel<<<dim3(48, 16, 1), 256, 0, stream>>>(hsb, WT, QKV, HIDN, HIDN, HIDN, QKV_N);

  // 4) RMSNorm + RoPE -> fp16 per-head layouts
  rope_norm_kernel<<<SLEN * NHEAD / 4, 256, 0, stream>>>(QKV, QKV_N, NHEAD, qw, cosb, sinb, eps, qf);
  rope_norm_kernel<<<SLEN * NKV / 4, 256, 0, stream>>>(QKV + 4096, QKV_N, NKV, kw, cosb, sinb, eps, kf);

  // 5) V^T per kv head: QKV[s][5120+kvh*128+d] -> Vt[kvh][d][s]
  transpose_kernel<<<dim3(32, 2, 8), 256, 0, stream>>>(QKV + 5120, 128, QKV_N, Vt, (long)HD * SLEN, SLEN);

  // 6) wo^T (QKV dead now)
  transpose_kernel<<<dim3(64, 64, 1), 256, 0, stream>>>(wo, 0, HIDN, WoT, 0, HIDN);

  // 7) flash attention (512 blocks, 2/CU, pipelined staging)
  flash_kernel<<<dim3(16, 32, 1), 256, 0, stream>>>(qf, kf, Vt, AO);

  // 8) output projection -> fp32 d_out
  gemm_kernel<<<dim3(32, 16, 1), 256, 0, stream>>>(AO, WoT, (float*)d_out, HIDN, HIDN, HIDN, HIDN);
}

// Round 8
// 478.315 us; speedup vs baseline: 1.2435x; 1.1367x over previous
//
#include <hip/hip_runtime.h>
#include <hip/hip_bf16.h>
#include <stdint.h>

#define SLEN 2048
#define HIDN 4096
#define NHEAD 32
#define NKV 8
#define HD 128
#define QKV_N 6144

typedef __hip_bfloat16 bf16;
typedef short short8 __attribute__((ext_vector_type(8)));
typedef _Float16 f16x8 __attribute__((ext_vector_type(8)));
typedef float f32x4 __attribute__((ext_vector_type(4)));
typedef float f32x16 __attribute__((ext_vector_type(16)));

__device__ __forceinline__ void gld16(const void* g, void* l) {
  __builtin_amdgcn_global_load_lds((const __attribute__((address_space(1))) void*)g,
                                   (__attribute__((address_space(3))) void*)l,
                                   16, 0, 0);
}

__device__ __forceinline__ unsigned short bfbits(float f) {
  bf16 h = __float2bfloat16(f);
  unsigned short u;
  __builtin_memcpy(&u, &h, 2);
  return u;
}
__device__ __forceinline__ unsigned int pack2(float a, float b) {
  return (unsigned int)bfbits(a) | ((unsigned int)bfbits(b) << 16);
}

// Plain bf16 MFMA GEMM: C[M,N](fp32) = A[M,K] * B[N,K]^T (m97 structure).
__global__ __launch_bounds__(256) void gemm_kernel(
    const bf16* __restrict__ A, const bf16* __restrict__ B,
    float* __restrict__ C, int K, int lda, int ldb, int ldc)
{
  __shared__ __align__(16) bf16 smem[2 * 4096];
  bf16* sA = smem;
  bf16* sB = smem + 4096;

  const int nwg = gridDim.x * gridDim.y;
  int bid = blockIdx.y * gridDim.x + blockIdx.x;
  {
    const int q = nwg >> 3, rr = nwg & 7, x = bid & 7, idx = bid >> 3;
    bid = (x < rr ? x * (q + 1) : rr * (q + 1) + (x - rr) * q) + idx;
  }
  const int bx = bid % gridDim.x;
  const int by = bid / gridDim.x;
  const int row0 = by * 128;
  const int col0 = bx * 128;

  const int tid = threadIdx.x;
  const int w = tid >> 6;
  const int lane = tid & 63;
  const int wr = w >> 1, wc = w & 1;

  f32x4 acc[4][4] = {};
  const int fr = lane & 15;
  const int fk = (lane >> 4) << 3;

  const int nk = K >> 5;
  for (int kt = 0; kt < nk; ++kt) {
    const int k0 = kt << 5;
#pragma unroll
    for (int i = 0; i < 2; ++i) {
      const int grp = (i << 2) + w;
      const int c = grp * 64 + lane;
      const int r = c >> 2;
      const int kk = k0 + ((c & 3) << 3);
      gld16(A + (long)(row0 + r) * lda + kk, sA + grp * 512);
      gld16(B + (long)(col0 + r) * ldb + kk, sB + grp * 512);
    }
    __syncthreads();
    short8 a[4], b[4];
#pragma unroll
    for (int m = 0; m < 4; ++m) {
      a[m] = *(const short8*)(sA + (wr * 64 + m * 16 + fr) * 32 + fk);
      b[m] = *(const short8*)(sB + (wc * 64 + m * 16 + fr) * 32 + fk);
    }
    __builtin_amdgcn_s_setprio(1);
#pragma unroll
    for (int m = 0; m < 4; ++m)
#pragma unroll
      for (int n = 0; n < 4; ++n)
        acc[m][n] = __builtin_amdgcn_mfma_f32_16x16x32_bf16(a[m], b[n], acc[m][n], 0, 0, 0);
    __builtin_amdgcn_s_setprio(0);
    __syncthreads();
  }

  const int cr = (lane >> 4) << 2;
  const int cc = lane & 15;
#pragma unroll
  for (int m = 0; m < 4; ++m)
#pragma unroll
    for (int n = 0; n < 4; ++n)
#pragma unroll
      for (int r = 0; r < 4; ++r) {
        const long row = row0 + wr * 64 + m * 16 + cr + r;
        const long col = col0 + wc * 64 + n * 16 + cc;
        C[row * (long)ldc + col] = acc[m][n][r];
      }
}

// dst[z][n][k] = bf16(src[z][k][n]), fp32 src. 64x64 tiles via LDS.
__global__ __launch_bounds__(256) void transpose_kernel(
    const float* __restrict__ src, long srcZ, int srcLd,
    bf16* __restrict__ dst, long dstZ, int dstLd)
{
  __shared__ float t[64][65];
  const int z = blockIdx.z;
  src += (long)z * srcZ;
  const long db = (long)z * dstZ;
  const int k0 = blockIdx.x * 64;
  const int n0 = blockIdx.y * 64;
  const int tx = threadIdx.x & 63;
  const int ty = threadIdx.x >> 6;
#pragma unroll
  for (int r = ty; r < 64; r += 4)
    t[r][tx] = src[(long)(k0 + r) * srcLd + n0 + tx];
  __syncthreads();
#pragma unroll
  for (int r = ty; r < 64; r += 4)
    dst[db + (long)(n0 + r) * dstLd + k0 + tx] = __float2bfloat16(t[tx][r]);
}

__global__ __launch_bounds__(256) void cvt_bf16_kernel(
    const float* __restrict__ x, bf16* __restrict__ y, int n)
{
  const int i = (blockIdx.x * 256 + threadIdx.x) * 4;
  if (i >= n) return;
  const f32x4 v = *(const f32x4*)(x + i);
#pragma unroll
  for (int j = 0; j < 4; ++j) y[i + j] = __float2bfloat16(v[j]);
}

// One wave per (s, head): RMSNorm over D=128 (fp32) then RoPE; fp16 out [head][s][d].
__global__ __launch_bounds__(256) void rope_norm_kernel(
    const float* __restrict__ x_, int ld, int nh,
    const float* __restrict__ nw, const float* __restrict__ cosb,
    const float* __restrict__ sinb, const float* __restrict__ epsp,
    _Float16* __restrict__ df)
{
  const int gw = blockIdx.x * 4 + (threadIdx.x >> 6);
  const int lane = threadIdx.x & 63;
  const int srow = gw / nh;
  const int head = gw - srow * nh;
  const float* x = x_ + (long)srow * ld + head * HD;
  const float x0 = x[lane];
  const float x1 = x[lane + 64];
  float ss = x0 * x0 + x1 * x1;
#pragma unroll
  for (int o = 32; o > 0; o >>= 1) ss += __shfl_xor(ss, o);
  const float rr = rsqrtf(ss * (1.0f / 128.0f) + epsp[0]);
  const float nv0 = x0 * rr * nw[lane];
  const float nv1 = x1 * rr * nw[lane + 64];
  const float c0 = cosb[srow * HD + lane];
  const float c1 = cosb[srow * HD + lane + 64];
  const float sn0 = sinb[srow * HD + lane];
  const float sn1 = sinb[srow * HD + lane + 64];
  const float o0 = nv0 * c0 - nv1 * sn0;
  const float o1 = nv1 * c1 + nv0 * sn1;
  const long base = ((long)head * SLEN + srow) * HD;
  df[base + lane] = (_Float16)o0;
  df[base + lane + 64] = (_Float16)o1;
}

// Flash v4: swapped-QK 32x32 in-register softmax (m214 structure).
// Block = 256 q-rows x head; 8 waves x 32 q-rows. KVBLK=64 double-buffered,
// counted vmcnt. S^T = mfma(K,Q) -> lane owns P-row for q=lane&31.
__global__ __launch_bounds__(512, 2) void flash_kernel(
    const _Float16* __restrict__ qf, const _Float16* __restrict__ kf,
    const bf16* __restrict__ vt,   // [kvh][d=128][s=2048]
    bf16* __restrict__ AO)         // [2048][4096]
{
  __shared__ __align__(16) _Float16 sK[2][64 * 128];  // [key][d], 16-slot rows, XOR row&15
  __shared__ __align__(16) bf16 sV[2][64 * 128];      // row-pair: [d>>1][(d&1)*8+kslot], XOR row&15
  __shared__ float sStat[8][32];

  // XCD remap: 32 consecutive blocks (one kvh) per XCD.
  const int lin = blockIdx.x;
  const int swz = (lin & 7) * 32 + (lin >> 3);
  const int kvh = swz >> 5;
  const int head = kvh * 4 + ((swz >> 3) & 3);
  const int qt = swz & 7;

  const int tid = threadIdx.x;
  const int w = tid >> 6;
  const int lane = tid & 63;
  const int q31 = lane & 31;
  const int hi = lane >> 5;

  // Q fragments (B-operand): row=q31, k = ks*16 + hi*8 + j
  f16x8 bq[8];
  {
    const long qb = ((long)head * SLEN + qt * 256 + w * 32 + q31) * HD + hi * 8;
#pragma unroll
    for (int ks = 0; ks < 8; ++ks)
      bq[ks] = *(const f16x8*)(qf + qb + ks * 16);
  }

  const _Float16* kb = kf + (long)kvh * SLEN * HD;
  const bf16* vb = vt + (long)kvh * HD * SLEN;

  auto stage = [&](int t, int buf) {
#pragma unroll
    for (int i = 0; i < 2; ++i) {          // K: 64x128 f16, 2 chunks/thread
      const int c = i * 512 + tid;
      const int row = c >> 4;
      const int sg = (c & 15) ^ (row & 15);
      gld16(kb + (long)(t * 64 + row) * HD + sg * 8,
            (_Float16*)sK[buf] + (i * 512 + w * 64) * 8);
    }
#pragma unroll
    for (int i = 0; i < 2; ++i) {          // V: row-pair layout
      const int c = i * 512 + tid;
      const int rp = c >> 4;
      const int sg = (c & 15) ^ (rp & 15);
      const int d = rp * 2 + (sg >> 3);
      gld16(vb + (long)d * SLEN + t * 64 + (sg & 7) * 8,
            (bf16*)sV[buf] + (i * 512 + w * 64) * 8);
    }
  };

  f32x16 o[4] = {};
  float m = -3.0e38f, l = 0.0f;

  stage(0, 0);
  stage(1, 1);
  asm volatile("s_waitcnt vmcnt(4)" ::: "memory");
  __builtin_amdgcn_sched_barrier(0);
  __builtin_amdgcn_s_barrier();
  __builtin_amdgcn_sched_barrier(0);

  for (int t = 0; t < SLEN / 64; ++t) {
    const int cur = t & 1;
    const _Float16* K = sK[cur];
    const bf16* V = sV[cur];

    // S^T[64key][32q] = mfma(K, Q): two key-tiles of 32
    f32x16 s0 = {}, s1 = {};
    __builtin_amdgcn_s_setprio(1);
#pragma unroll
    for (int ks = 0; ks < 8; ++ks) {
      const int slot = (2 * ks + hi) ^ (q31 & 15);
      const f16x8 a0 = *(const f16x8*)(K + q31 * 128 + slot * 8);
      const f16x8 a1 = *(const f16x8*)(K + (32 + q31) * 128 + slot * 8);
      s0 = __builtin_amdgcn_mfma_f32_32x32x16_f16(a0, bq[ks], s0, 0, 0, 0);
      s1 = __builtin_amdgcn_mfma_f32_32x32x16_f16(a1, bq[ks], s1, 0, 0, 0);
    }
    __builtin_amdgcn_s_setprio(0);

    // lane-local row stats (q = q31); partner half via one shfl
    float pmax = s0[0];
#pragma unroll
    for (int r = 1; r < 16; ++r) pmax = fmaxf(pmax, s0[r]);
#pragma unroll
    for (int r = 0; r < 16; ++r) pmax = fmaxf(pmax, s1[r]);
    pmax = fmaxf(pmax, __shfl_xor(pmax, 32));

    if (!__all(pmax - m <= 8.0f)) {   // defer-max (T13)
      const float mnew = fmaxf(m, pmax);
      const float corr = __expf(m - mnew);
      m = mnew;
      l *= corr;
      sStat[w][q31] = corr;
      asm volatile("s_waitcnt lgkmcnt(0)" ::: "memory");
      __builtin_amdgcn_sched_barrier(0);
      f32x4 c4[4];
#pragma unroll
      for (int rr = 0; rr < 4; ++rr)
        c4[rr] = *(const f32x4*)&sStat[w][8 * rr + 4 * hi];
#pragma unroll
      for (int nt = 0; nt < 4; ++nt)
#pragma unroll
        for (int r = 0; r < 16; ++r) o[nt][r] *= c4[r >> 2][r & 3];
    }

    float psum = 0.0f;
#pragma unroll
    for (int r = 0; r < 16; ++r) { s0[r] = __expf(s0[r] - m); psum += s0[r]; }
#pragma unroll
    for (int r = 0; r < 16; ++r) { s1[r] = __expf(s1[r] - m); psum += s1[r]; }
    psum += __shfl_xor(psum, 32);
    l += psum;

    // pack P -> bf16 words; partner words via shfl_xor(32)
    unsigned int pk[16], sw[16];
#pragma unroll
    for (int i = 0; i < 8; ++i) pk[i] = pack2(s0[2 * i], s0[2 * i + 1]);
#pragma unroll
    for (int i = 0; i < 8; ++i) pk[8 + i] = pack2(s1[2 * i], s1[2 * i + 1]);
#pragma unroll
    for (int i = 0; i < 16; ++i) sw[i] = __shfl_xor((int)pk[i], 32);

    // A-frags: a[ks] keys 16ks+8hi+j ; j<4 from hi=0 lane regs 8(ks&1)+4hi+j, j>=4 from hi=1
    short8 pa[4];
#pragma unroll
    for (int ks = 0; ks < 4; ++ks) {
      const int base = (ks >> 1) * 8 + (ks & 1) * 4 + 2 * hi;
      union { unsigned int u[4]; short8 v; } tu;
      if (hi == 0) {
        tu.u[0] = pk[base]; tu.u[1] = pk[base + 1];
        tu.u[2] = sw[base]; tu.u[3] = sw[base + 1];
      } else {
        tu.u[0] = sw[base]; tu.u[1] = sw[base + 1];
        tu.u[2] = pk[base]; tu.u[3] = pk[base + 1];
      }
      pa[ks] = tu.v;
    }

    // O[32q][128d] += P V : B-frag row=d (row-pair LDS), k=keys
    __builtin_amdgcn_s_setprio(1);
#pragma unroll
    for (int nt = 0; nt < 4; ++nt) {
      const int d = nt * 32 + q31;
      const int rp = d >> 1;
      const int sbase = ((d & 1) << 3) + hi;
#pragma unroll
      for (int ks = 0; ks < 4; ++ks) {
        const int slot = (sbase + 2 * ks) ^ (rp & 15);
        const short8 bv = *(const short8*)(V + rp * 128 + slot * 8);
        o[nt] = __builtin_amdgcn_mfma_f32_32x32x16_bf16(pa[ks], bv, o[nt], 0, 0, 0);
      }
    }
    __builtin_amdgcn_s_setprio(0);

    __builtin_amdgcn_s_barrier();
    __builtin_amdgcn_sched_barrier(0);
    if (t + 2 < SLEN / 64) {
      stage(t + 2, cur);
      asm volatile("s_waitcnt vmcnt(4)" ::: "memory");
    } else {
      asm volatile("s_waitcnt vmcnt(0)" ::: "memory");
    }
    __builtin_amdgcn_sched_barrier(0);
    __builtin_amdgcn_s_barrier();
    __builtin_amdgcn_sched_barrier(0);
  }

  // epilogue: per-row 1/l via LDS broadcast (rows crow(r,hi) = (r&3)+8(r>>2)+4hi)
  sStat[w][q31] = l;
  asm volatile("s_waitcnt lgkmcnt(0)" ::: "memory");
  __builtin_amdgcn_sched_barrier(0);
  f32x4 l4[4];
#pragma unroll
  for (int rr = 0; rr < 4; ++rr) {
    const f32x4 lv = *(const f32x4*)&sStat[w][8 * rr + 4 * hi];
#pragma unroll
    for (int j = 0; j < 4; ++j) l4[rr][j] = 1.0f / lv[j];
  }
#pragma unroll
  for (int nt = 0; nt < 4; ++nt)
#pragma unroll
    for (int rr = 0; rr < 4; ++rr)
#pragma unroll
      for (int j = 0; j < 4; ++j) {
        const long row = qt * 256 + w * 32 + 8 * rr + 4 * hi + j;
        AO[row * HIDN + head * 128 + nt * 32 + q31] =
            __float2bfloat16(o[nt][rr * 4 + j] * l4[rr][j]);
      }
}

extern "C" void kernel_launch(void* const* d_in, const int* in_sizes, int n_in,
                              void* d_out, int out_size, void* d_ws, size_t ws_size,
                              hipStream_t stream)
{
  const float* hs   = (const float*)d_in[0];
  const float* cosb = (const float*)d_in[1];
  const float* sinb = (const float*)d_in[2];
  const float* wq   = (const float*)d_in[3];
  const float* wk   = (const float*)d_in[4];
  const float* wv   = (const float*)d_in[5];
  const float* wo   = (const float*)d_in[6];
  const float* qw   = (const float*)d_in[7];
  const float* kw   = (const float*)d_in[8];
  const float* eps  = (const float*)d_in[9];

  const size_t MB = 1024 * 1024;
  if (ws_size < 116 * MB) return;  // known-good budget
  uint8_t* ws = (uint8_t*)d_ws;

  bf16*  hsb = (bf16*)(ws + 0 * MB);        // [2048][4096]        16 MiB
  bf16*  WT  = (bf16*)(ws + 16 * MB);       // [6144][4096]        48 MiB
  float* QKV = (float*)(ws + 64 * MB);      // [2048][6144] f32    48 MiB
  _Float16* qf = (_Float16*)(ws + 16 * MB); // [32][2048][128]     16 MiB
  _Float16* kf = (_Float16*)(ws + 32 * MB); // [8][2048][128]       4 MiB
  bf16*  Vt  = (bf16*)(ws + 36 * MB);       // [8][128][2048]       4 MiB
  bf16*  AO  = (bf16*)(ws + 64 * MB);       // [2048][4096]        16 MiB
  bf16*  WoT = (bf16*)(ws + 80 * MB);       // [4096][4096]        32 MiB (peak 112 MiB)

  cvt_bf16_kernel<<<SLEN * HIDN / 4 / 256, 256, 0, stream>>>(hs, hsb, SLEN * HIDN);

  transpose_kernel<<<dim3(64, 64, 1), 256, 0, stream>>>(wq, 0, HIDN, WT, 0, HIDN);
  transpose_kernel<<<dim3(64, 16, 1), 256, 0, stream>>>(wk, 0, 1024, WT + (size_t)4096 * HIDN, 0, HIDN);
  transpose_kernel<<<dim3(64, 16, 1), 256, 0, stream>>>(wv, 0, 1024, WT + (size_t)5120 * HIDN, 0, HIDN);

  gemm_kernel<<<dim3(48, 16, 1), 256, 0, stream>>>(hsb, WT, QKV, HIDN, HIDN, HIDN, QKV_N);

  rope_norm_kernel<<<SLEN * NHEAD / 4, 256, 0, stream>>>(QKV, QKV_N, NHEAD, qw, cosb, sinb, eps, qf);
  rope_norm_kernel<<<SLEN * NKV / 4, 256, 0, stream>>>(QKV + 4096, QKV_N, NKV, kw, cosb, sinb, eps, kf);

  transpose_kernel<<<dim3(32, 2, 8), 256, 0, stream>>>(QKV + 5120, 128, QKV_N, Vt, (long)HD * SLEN, SLEN);

  transpose_kernel<<<dim3(64, 64, 1), 256, 0, stream>>>(wo, 0, HIDN, WoT, 0, HIDN);

  // flash: 256 blocks x 512 threads (8 waves), 1/CU
  flash_kernel<<<dim3(256, 1, 1), 512, 0, stream>>>(qf, kf, Vt, AO);

  gemm_kernel<<<dim3(32, 16, 1), 256, 0, stream>>>(AO, WoT, (float*)d_out, HIDN, HIDN, HIDN, HIDN);
}